// Round 1
// baseline (566.441 us; speedup 1.0000x reference)
//
#include <hip/hip_runtime.h>
#include <hip/hip_bf16.h>
#include <math.h>

// Problem dims (fixed)
constexpr int NB  = 8;    // batch
constexpr int NR  = 128;  // rule-graph nodes
constexpr int HID = 256;  // hidden
constexpr int NIN = 512;  // input dim
constexpr int NHD = 4;    // attention heads
constexpr int DHD = 64;   // head dim
constexpr int NL  = 3;    // layers

// ---------------------------------------------------------------------------
// Adjacency: Aw[i,j] = sigmoid(adj[i,j]) * (i!=j); rowsum[i] = sum_j Aw[i,j]
// ---------------------------------------------------------------------------
__global__ __launch_bounds__(128) void adj_kernel(
    const float* __restrict__ adj, float* __restrict__ Aw, float* __restrict__ rowsum)
{
    int i = blockIdx.x;
    int j = threadIdx.x;  // 0..127
    float x = adj[i * NR + j];
    float s = 1.0f / (1.0f + expf(-x));
    if (j == i) s = 0.0f;
    Aw[i * NR + j] = s;
    float t = s;
#pragma unroll
    for (int off = 32; off; off >>= 1) t += __shfl_xor(t, off);
    __shared__ float red[2];
    if ((j & 63) == 0) red[j >> 6] = t;
    __syncthreads();
    if (j == 0) rowsum[i] = red[0] + red[1];
}

// ---------------------------------------------------------------------------
// Encoder: h0 = x @ We + be  (M=8, K=512, N=256), broadcast to h[b,r,:]
// ---------------------------------------------------------------------------
__global__ __launch_bounds__(256) void encoder_kernel(
    const float* __restrict__ x, const float* __restrict__ We,
    const float* __restrict__ be, float* __restrict__ h)
{
    int b = blockIdx.x;   // 0..7
    int t = threadIdx.x;  // 0..255
    __shared__ float xs[NIN];
    for (int k = t; k < NIN; k += 256) xs[k] = x[b * NIN + k];
    __syncthreads();
    float acc = be[t];
#pragma unroll 4
    for (int k = 0; k < NIN; ++k) acc += xs[k] * We[k * HID + t];
    float* hb = &h[(size_t)b * NR * HID];
    for (int r = 0; r < NR; ++r) hb[(size_t)r * HID + t] = acc;
}

// ---------------------------------------------------------------------------
// Generic fused fp32 GEMM. C = [A | A2] @ B + bias*rowscale, optional relu.
// A: [M,K] row-major (stride K), A2: [M,K2] (stride K2) or null.
// B: [(K+K2), N] row-major. Up to 3 (B,bias,C) triples selected by blockIdx.z.
// Tiles: 64x64 per block, 256 threads, 4x4 per thread, BK=16.
// M, N multiples of 64; K, K2 multiples of 16.
// ---------------------------------------------------------------------------
__global__ __launch_bounds__(256) void gemm_fused(
    const float* __restrict__ A, int K,
    const float* __restrict__ A2, int K2,
    const float* __restrict__ B0, const float* __restrict__ B1, const float* __restrict__ B2,
    const float* __restrict__ bias0, const float* __restrict__ bias1, const float* __restrict__ bias2,
    float* __restrict__ C0, float* __restrict__ C1, float* __restrict__ C2,
    int N, const float* __restrict__ rowscale, int rs_mask, int relu)
{
    int z = blockIdx.z;
    const float* Bw   = (z == 0) ? B0 : (z == 1) ? B1 : B2;
    const float* bias = (z == 0) ? bias0 : (z == 1) ? bias1 : bias2;
    float* C          = (z == 0) ? C0 : (z == 1) ? C1 : C2;

    __shared__ float As[16][68];  // transposed A tile, padded to 68 for alignment
    __shared__ float Bs[16][64];

    int tid = threadIdx.x;
    int tx = tid & 15, ty = tid >> 4;
    int m0 = blockIdx.y * 64;
    int n0 = blockIdx.x * 64;

    float acc[4][4] = {};

    for (int seg = 0; seg < 2; ++seg) {
        const float* Ain = seg ? A2 : A;
        int Kseg = seg ? K2 : K;
        if (Ain == nullptr || Kseg == 0) continue;
        int krow_base = seg ? K : 0;
        int arow = tid >> 2, acol = (tid & 3) << 2;  // 64 rows x 16 cols
        int brow = tid >> 4, bcol = (tid & 15) << 2; // 16 rows x 64 cols
        for (int k0 = 0; k0 < Kseg; k0 += 16) {
            float4 av = *(const float4*)&Ain[(size_t)(m0 + arow) * Kseg + k0 + acol];
            As[acol + 0][arow] = av.x;
            As[acol + 1][arow] = av.y;
            As[acol + 2][arow] = av.z;
            As[acol + 3][arow] = av.w;
            float4 bv = *(const float4*)&Bw[(size_t)(krow_base + k0 + brow) * N + n0 + bcol];
            *(float4*)&Bs[brow][bcol] = bv;
            __syncthreads();
#pragma unroll
            for (int kk = 0; kk < 16; ++kk) {
                float4 af = *(const float4*)&As[kk][ty << 2];
                float4 bf = *(const float4*)&Bs[kk][tx << 2];
                float a_[4] = {af.x, af.y, af.z, af.w};
                float b_[4] = {bf.x, bf.y, bf.z, bf.w};
#pragma unroll
                for (int i = 0; i < 4; ++i)
#pragma unroll
                    for (int j = 0; j < 4; ++j) acc[i][j] += a_[i] * b_[j];
            }
            __syncthreads();
        }
    }

#pragma unroll
    for (int i = 0; i < 4; ++i) {
        int m = m0 + (ty << 2) + i;
        float rs = rowscale ? rowscale[m & rs_mask] : 1.0f;
        float4 o;
        float v[4];
#pragma unroll
        for (int j = 0; j < 4; ++j) {
            int n = n0 + (tx << 2) + j;
            float val = acc[i][j];
            if (bias) val += bias[n] * rs;
            if (relu) val = fmaxf(val, 0.0f);
            v[j] = val;
        }
        o.x = v[0]; o.y = v[1]; o.z = v[2]; o.w = v[3];
        *(float4*)&C[(size_t)m * N + n0 + (tx << 2)] = o;
    }
}

// ---------------------------------------------------------------------------
// aggpre[b,i,h] = sum_j Aw[i,j] * relu(a[b,i,h] + bb[b,j,h] + b1[h])
// block: (i-group of 4, b); thread: h
// ---------------------------------------------------------------------------
__global__ __launch_bounds__(256) void aggregate_kernel(
    const float* __restrict__ a, const float* __restrict__ bbv,
    const float* __restrict__ b1, const float* __restrict__ Aw,
    float* __restrict__ aggpre)
{
    int b  = blockIdx.y;       // 0..7
    int i0 = blockIdx.x * 4;   // 0..124
    int h  = threadIdx.x;      // 0..255
    float bias = b1[h];
    float ai[4], acc[4] = {0.f, 0.f, 0.f, 0.f};
#pragma unroll
    for (int ii = 0; ii < 4; ++ii)
        ai[ii] = a[((size_t)b * NR + i0 + ii) * HID + h] + bias;
    const float* bbb = &bbv[(size_t)b * NR * HID + h];
#pragma unroll 2
    for (int j = 0; j < NR; ++j) {
        float bj = bbb[(size_t)j * HID];
#pragma unroll
        for (int ii = 0; ii < 4; ++ii) {
            float pre = fmaxf(ai[ii] + bj, 0.0f);
            acc[ii] += Aw[(i0 + ii) * NR + j] * pre;
        }
    }
#pragma unroll
    for (int ii = 0; ii < 4; ++ii)
        aggpre[((size_t)b * NR + i0 + ii) * HID + h] = acc[ii];
}

// ---------------------------------------------------------------------------
// h = layernorm(h + u) * g + b   (per row of 256)
// ---------------------------------------------------------------------------
__global__ __launch_bounds__(256) void resid_ln_kernel(
    float* __restrict__ h, const float* __restrict__ u,
    const float* __restrict__ g, const float* __restrict__ bta)
{
    int row = blockIdx.x;   // 0..1023
    int t = threadIdx.x;    // 0..255
    size_t idx = (size_t)row * HID + t;
    float v = h[idx] + u[idx];
    __shared__ float red[8];
    float s = v;
#pragma unroll
    for (int off = 32; off; off >>= 1) s += __shfl_xor(s, off);
    int wave = t >> 6, lane = t & 63;
    if (lane == 0) red[wave] = s;
    __syncthreads();
    float mu = (red[0] + red[1] + red[2] + red[3]) * (1.0f / HID);
    float d = v - mu;
    float s2 = d * d;
#pragma unroll
    for (int off = 32; off; off >>= 1) s2 += __shfl_xor(s2, off);
    if (lane == 0) red[4 + wave] = s2;
    __syncthreads();
    float var = (red[4] + red[5] + red[6] + red[7]) * (1.0f / HID);
    h[idx] = d * rsqrtf(var + 1e-5f) * g[t] + bta[t];
}

// ---------------------------------------------------------------------------
// Attention scores + softmax: S[b,hd,i,j] = softmax_j(q_i . k_j / 8)
// block: (i, b*NHD+hd), 128 threads (j)
// ---------------------------------------------------------------------------
__global__ __launch_bounds__(128) void attn_score_kernel(
    const float* __restrict__ q, const float* __restrict__ k, float* __restrict__ S)
{
    int i  = blockIdx.x;          // 0..127
    int bh = blockIdx.y;          // 0..31 = b*4+hd
    int b = bh >> 2, hd = bh & 3;
    int j = threadIdx.x;          // 0..127
    __shared__ float qs[DHD];
    if (j < DHD) qs[j] = q[((size_t)(b * NR + i)) * HID + hd * DHD + j];
    __syncthreads();
    const float4* k4 = (const float4*)&k[((size_t)(b * NR + j)) * HID + hd * DHD];
    const float4* q4 = (const float4*)qs;
    float acc = 0.f;
#pragma unroll
    for (int d4 = 0; d4 < DHD / 4; ++d4) {
        float4 kv = k4[d4];
        float4 qv = q4[d4];
        acc += qv.x * kv.x + qv.y * kv.y + qv.z * kv.z + qv.w * kv.w;
    }
    acc *= 0.125f;  // 1/sqrt(64)
    __shared__ float red[4];
    float m = acc;
#pragma unroll
    for (int off = 32; off; off >>= 1) m = fmaxf(m, __shfl_xor(m, off));
    if ((j & 63) == 0) red[j >> 6] = m;
    __syncthreads();
    m = fmaxf(red[0], red[1]);
    float e = expf(acc - m);
    float s = e;
#pragma unroll
    for (int off = 32; off; off >>= 1) s += __shfl_xor(s, off);
    if ((j & 63) == 0) red[2 + (j >> 6)] = s;
    __syncthreads();
    s = red[2] + red[3];
    S[((size_t)bh * NR + i) * NR + j] = e / s;
}

// ---------------------------------------------------------------------------
// pooled[b,i,hd*64+d] = sum_j S[b,hd,i,j] * v[b,j,hd*64+d]
// block: b*R+i; thread: t = hd*64+d
// ---------------------------------------------------------------------------
__global__ __launch_bounds__(256) void attn_pv_kernel(
    const float* __restrict__ S, const float* __restrict__ v, float* __restrict__ pooled)
{
    int bi = blockIdx.x;   // 0..1023
    int b = bi >> 7, i = bi & 127;
    int t = threadIdx.x;   // 0..255
    int hd = t >> 6;
    const float* Prow = &S[(((size_t)(b * NHD + hd)) * NR + i) * NR];
    const float* vb = &v[(size_t)b * NR * HID + t];
    float acc = 0.f;
#pragma unroll 4
    for (int j = 0; j < NR; ++j) acc += Prow[j] * vb[(size_t)j * HID];
    pooled[(size_t)bi * HID + t] = acc;
}

// ---------------------------------------------------------------------------
// Readout: g = mean_r pooled_o; t = relu(g@W1+b1); logits = t@W2+b2; softmax
// block per batch (8), 256 threads
// ---------------------------------------------------------------------------
__global__ __launch_bounds__(256) void readout_kernel(
    const float* __restrict__ pooled_o,
    const float* __restrict__ W1, const float* __restrict__ b1,
    const float* __restrict__ W2, const float* __restrict__ b2,
    float* __restrict__ out)
{
    int b = blockIdx.x;
    int t = threadIdx.x;
    __shared__ float gs[HID];
    __shared__ float ts[HID];
    __shared__ float red[8];
    const float* pb = &pooled_o[(size_t)b * NR * HID + t];
    float s = 0.f;
#pragma unroll 4
    for (int r = 0; r < NR; ++r) s += pb[(size_t)r * HID];
    gs[t] = s * (1.0f / NR);
    __syncthreads();
    float acc = b1[t];
#pragma unroll 4
    for (int k = 0; k < HID; ++k) acc += gs[k] * W1[k * HID + t];
    ts[t] = fmaxf(acc, 0.0f);
    __syncthreads();
    float logit = -1e30f;
    if (t < NR) {
        logit = b2[t];
#pragma unroll 4
        for (int k = 0; k < HID; ++k) logit += ts[k] * W2[k * NR + t];
    }
    float m = logit;
#pragma unroll
    for (int off = 32; off; off >>= 1) m = fmaxf(m, __shfl_xor(m, off));
    if ((t & 63) == 0) red[t >> 6] = m;
    __syncthreads();
    m = fmaxf(red[0], red[1]);   // waves 0,1 hold t<128
    float e = (t < NR) ? expf(logit - m) : 0.0f;
    float ssum = e;
#pragma unroll
    for (int off = 32; off; off >>= 1) ssum += __shfl_xor(ssum, off);
    if ((t & 63) == 0) red[4 + (t >> 6)] = ssum;
    __syncthreads();
    float tot = red[4] + red[5];
    if (t < NR) out[b * NR + t] = e / tot;
}

// ---------------------------------------------------------------------------
extern "C" void kernel_launch(void* const* d_in, const int* in_sizes, int n_in,
                              void* d_out, int out_size, void* d_ws, size_t ws_size,
                              hipStream_t stream)
{
    const float* x        = (const float*)d_in[0];
    const float* We       = (const float*)d_in[1];
    const float* be       = (const float*)d_in[2];
    const float* msg_W1   = (const float*)d_in[3];
    const float* msg_b1   = (const float*)d_in[4];
    const float* msg_W2   = (const float*)d_in[5];
    const float* msg_b2   = (const float*)d_in[6];
    const float* upd_W1   = (const float*)d_in[7];
    const float* upd_b1   = (const float*)d_in[8];
    const float* upd_W2   = (const float*)d_in[9];
    const float* upd_b2   = (const float*)d_in[10];
    const float* ln_g     = (const float*)d_in[11];
    const float* ln_b     = (const float*)d_in[12];
    const float* rule_adj = (const float*)d_in[13];
    const float* Wq       = (const float*)d_in[14];
    const float* bq       = (const float*)d_in[15];
    const float* Wk       = (const float*)d_in[16];
    const float* bk       = (const float*)d_in[17];
    const float* Wv       = (const float*)d_in[18];
    const float* bv       = (const float*)d_in[19];
    const float* Wo       = (const float*)d_in[20];
    const float* bo       = (const float*)d_in[21];
    const float* ro_W1    = (const float*)d_in[22];
    const float* ro_b1    = (const float*)d_in[23];
    const float* ro_W2    = (const float*)d_in[24];
    const float* ro_b2    = (const float*)d_in[25];
    float* out = (float*)d_out;

    constexpr size_t SZ = (size_t)NB * NR * HID;  // 262144
    float* ws   = (float*)d_ws;
    float* h    = ws;               // h state
    float* buf1 = h    + SZ;        // a  / q
    float* buf2 = buf1 + SZ;        // bb / k
    float* buf3 = buf2 + SZ;        // aggpre / v
    float* buf4 = buf3 + SZ;        // agg / pooled
    float* buf5 = buf4 + SZ;        // u1 / pooled_out
    float* buf6 = buf5 + SZ;        // u
    float* Sbuf = buf6 + SZ;        // [B,NH,R,R] = 524288
    float* Aw   = Sbuf + (size_t)NB * NHD * NR * NR;
    float* rsum = Aw + NR * NR;

    dim3 gemm_block(256);

    adj_kernel<<<dim3(NR), 128, 0, stream>>>(rule_adj, Aw, rsum);
    encoder_kernel<<<dim3(NB), 256, 0, stream>>>(x, We, be, h);

    for (int l = 0; l < NL; ++l) {
        const float* mW1 = msg_W1 + (size_t)l * 2 * HID * HID;
        const float* mb1 = msg_b1 + (size_t)l * HID;
        const float* mW2 = msg_W2 + (size_t)l * HID * HID;
        const float* mb2 = msg_b2 + (size_t)l * HID;
        const float* uW1 = upd_W1 + (size_t)l * 2 * HID * HID;
        const float* ub1 = upd_b1 + (size_t)l * HID;
        const float* uW2 = upd_W2 + (size_t)l * HID * HID;
        const float* ub2 = upd_b2 + (size_t)l * HID;
        const float* lg  = ln_g + (size_t)l * HID;
        const float* lb  = ln_b + (size_t)l * HID;

        // a = h @ W1a ; bb = h @ W1b   (dual GEMM, no bias)
        gemm_fused<<<dim3(4, 16, 2), gemm_block, 0, stream>>>(
            h, HID, nullptr, 0,
            mW1, mW1 + (size_t)HID * HID, nullptr,
            nullptr, nullptr, nullptr,
            buf1, buf2, nullptr,
            HID, nullptr, 0, 0);

        // aggpre = sum_j A[i,j] * relu(a_i + bb_j + b1)
        aggregate_kernel<<<dim3(NR / 4, NB), 256, 0, stream>>>(buf1, buf2, mb1, Aw, buf3);

        // agg = aggpre @ W2 + rowsum(A)[i] * b2
        gemm_fused<<<dim3(4, 16, 1), gemm_block, 0, stream>>>(
            buf3, HID, nullptr, 0,
            mW2, nullptr, nullptr,
            mb2, nullptr, nullptr,
            buf4, nullptr, nullptr,
            HID, rsum, NR - 1, 0);

        // u1 = relu([h | agg] @ upd_W1 + ub1)
        gemm_fused<<<dim3(4, 16, 1), gemm_block, 0, stream>>>(
            h, HID, buf4, HID,
            uW1, nullptr, nullptr,
            ub1, nullptr, nullptr,
            buf5, nullptr, nullptr,
            HID, nullptr, 0, 1);

        // u = u1 @ upd_W2 + ub2
        gemm_fused<<<dim3(4, 16, 1), gemm_block, 0, stream>>>(
            buf5, HID, nullptr, 0,
            uW2, nullptr, nullptr,
            ub2, nullptr, nullptr,
            buf6, nullptr, nullptr,
            HID, nullptr, 0, 0);

        // h = LN(h + u)
        resid_ln_kernel<<<dim3(NB * NR), 256, 0, stream>>>(h, buf6, lg, lb);
    }

    // q,k,v projections (triple GEMM)
    gemm_fused<<<dim3(4, 16, 3), gemm_block, 0, stream>>>(
        h, HID, nullptr, 0,
        Wq, Wk, Wv,
        bq, bk, bv,
        buf1, buf2, buf3,
        HID, nullptr, 0, 0);

    attn_score_kernel<<<dim3(NR, NB * NHD), 128, 0, stream>>>(buf1, buf2, Sbuf);
    attn_pv_kernel<<<dim3(NB * NR), 256, 0, stream>>>(Sbuf, buf3, buf4);

    // out projection: pooled @ Wo + bo
    gemm_fused<<<dim3(4, 16, 1), gemm_block, 0, stream>>>(
        buf4, HID, nullptr, 0,
        Wo, nullptr, nullptr,
        bo, nullptr, nullptr,
        buf5, nullptr, nullptr,
        HID, nullptr, 0, 0);

    readout_kernel<<<dim3(NB), 256, 0, stream>>>(buf5, ro_W1, ro_b1, ro_W2, ro_b2, out);
}

// Round 2
// 428.607 us; speedup vs baseline: 1.3216x; 1.3216x over previous
//
#include <hip/hip_runtime.h>
#include <hip/hip_bf16.h>
#include <math.h>

// Problem dims (fixed)
constexpr int NB  = 8;    // batch
constexpr int NR  = 128;  // rule-graph nodes
constexpr int HID = 256;  // hidden
constexpr int NIN = 512;  // input dim
constexpr int NHD = 4;    // attention heads
constexpr int DHD = 64;   // head dim
constexpr int NL  = 3;    // layers

// ---------------------------------------------------------------------------
// Adjacency: Aw[i,j] = sigmoid(adj[i,j]) * (i!=j); rowsum[i] = sum_j Aw[i,j]
// ---------------------------------------------------------------------------
__global__ __launch_bounds__(128) void adj_kernel(
    const float* __restrict__ adj, float* __restrict__ Aw, float* __restrict__ rowsum)
{
    int i = blockIdx.x;
    int j = threadIdx.x;  // 0..127
    float x = adj[i * NR + j];
    float s = 1.0f / (1.0f + expf(-x));
    if (j == i) s = 0.0f;
    Aw[i * NR + j] = s;
    float t = s;
#pragma unroll
    for (int off = 32; off; off >>= 1) t += __shfl_xor(t, off);
    __shared__ float red[2];
    if ((j & 63) == 0) red[j >> 6] = t;
    __syncthreads();
    if (j == 0) rowsum[i] = red[0] + red[1];
}

// ---------------------------------------------------------------------------
// Wave-split GEMV helper: y[0..255] = act(xs @ W + bias)
// W row-major [K,256] in global. Each wave owns K/4 rows; lane l covers
// outputs 4l..4l+3 (float4). Cross-wave reduce through LDS `red` (1024 fl).
// All 256 threads must call. xs must be sync'd before call.
// ---------------------------------------------------------------------------
__device__ __forceinline__ void gemv256(
    const float* xs, const float* __restrict__ W, int K,
    const float* __restrict__ bias, int relu, float* ys, float* red)
{
    int tid = threadIdx.x;
    int w = tid >> 6, l = tid & 63;
    int kpw = K >> 2;
    float4 acc = {0.f, 0.f, 0.f, 0.f};
    const float* Wp = W + (size_t)(w * kpw) * HID + l * 4;
    const float* xp = xs + w * kpw;
#pragma unroll 8
    for (int kk = 0; kk < kpw; ++kk) {
        float xv = xp[kk];
        float4 wv = *(const float4*)(Wp + (size_t)kk * HID);
        acc.x += xv * wv.x; acc.y += xv * wv.y;
        acc.z += xv * wv.z; acc.w += xv * wv.w;
    }
    *(float4*)&red[w * 256 + l * 4] = acc;
    __syncthreads();
    float v = red[tid] + red[256 + tid] + red[512 + tid] + red[768 + tid];
    if (bias) v += bias[tid];
    if (relu) v = fmaxf(v, 0.0f);
    ys[tid] = v;
    __syncthreads();
}

// ---------------------------------------------------------------------------
// Head: per-batch fused chain (layer-0 collapse).
//   h0 = x@We+be
//   p0 = relu(h0 @ (W1a+W1b) + mb1)       [one K=512 GEMV with xs=[h0|h0]]
//   m0 = p0@mW2 + mb2
//   c0 = h0@uW1a ; c1 = m0@uW1b
// Writes h0g, c0g, c1g [8,256] each.
// ---------------------------------------------------------------------------
__global__ __launch_bounds__(256) void head_kernel(
    const float* __restrict__ x, const float* __restrict__ We, const float* __restrict__ be,
    const float* __restrict__ mW1, const float* __restrict__ mb1,
    const float* __restrict__ mW2, const float* __restrict__ mb2,
    const float* __restrict__ uW1,
    float* __restrict__ h0g, float* __restrict__ c0g, float* __restrict__ c1g)
{
    int b = blockIdx.x;
    int t = threadIdx.x;
    __shared__ float xs[NIN];
    __shared__ float h0s[HID], p0s[HID], m0s[HID], c0s[HID], c1s[HID];
    __shared__ float red[1024];

    // stage E: h0 = x@We + be   (K=512)
    xs[t] = x[b * NIN + t];
    xs[256 + t] = x[b * NIN + 256 + t];
    __syncthreads();
    gemv256(xs, We, NIN, be, 0, h0s, red);

    // stage A: p0 = relu([h0|h0] @ mW1 + mb1)   (K=512)
    xs[t] = h0s[t];
    xs[256 + t] = h0s[t];
    __syncthreads();
    gemv256(xs, mW1, NIN, mb1, 1, p0s, red);

    // stage M: m0 = p0@mW2 + mb2
    gemv256(p0s, mW2, HID, mb2, 0, m0s, red);

    // stage C: c0 = h0@uW1a ; c1 = m0@uW1b
    gemv256(h0s, uW1, HID, nullptr, 0, c0s, red);
    gemv256(m0s, uW1 + (size_t)HID * HID, HID, nullptr, 0, c1s, red);

    h0g[b * HID + t] = h0s[t];
    c0g[b * HID + t] = c0s[t];
    c1g[b * HID + t] = c1s[t];
}

// ---------------------------------------------------------------------------
// u1[b,i,t] = relu(c0[b,t] + rowsum[i]*c1[b,t] + ub1[t])
// ---------------------------------------------------------------------------
__global__ __launch_bounds__(256) void u1_bcast_kernel(
    const float* __restrict__ c0g, const float* __restrict__ c1g,
    const float* __restrict__ rsum, const float* __restrict__ ub1,
    float* __restrict__ u1)
{
    int i = blockIdx.x, b = blockIdx.y;
    int t = threadIdx.x;
    float v = c0g[b * HID + t] + rsum[i] * c1g[b * HID + t] + ub1[t];
    u1[((size_t)(b * NR + i)) * HID + t] = fmaxf(v, 0.0f);
}

// ---------------------------------------------------------------------------
// Generic fused fp32 GEMM. C = [A | A2] @ B + bias*rowscale, optional relu.
// ---------------------------------------------------------------------------
__global__ __launch_bounds__(256) void gemm_fused(
    const float* __restrict__ A, int K,
    const float* __restrict__ A2, int K2,
    const float* __restrict__ B0, const float* __restrict__ B1, const float* __restrict__ B2,
    const float* __restrict__ bias0, const float* __restrict__ bias1, const float* __restrict__ bias2,
    float* __restrict__ C0, float* __restrict__ C1, float* __restrict__ C2,
    int N, const float* __restrict__ rowscale, int rs_mask, int relu)
{
    int z = blockIdx.z;
    const float* Bw   = (z == 0) ? B0 : (z == 1) ? B1 : B2;
    const float* bias = (z == 0) ? bias0 : (z == 1) ? bias1 : bias2;
    float* C          = (z == 0) ? C0 : (z == 1) ? C1 : C2;

    __shared__ float As[16][68];
    __shared__ float Bs[16][64];

    int tid = threadIdx.x;
    int tx = tid & 15, ty = tid >> 4;
    int m0 = blockIdx.y * 64;
    int n0 = blockIdx.x * 64;

    float acc[4][4] = {};

    for (int seg = 0; seg < 2; ++seg) {
        const float* Ain = seg ? A2 : A;
        int Kseg = seg ? K2 : K;
        if (Ain == nullptr || Kseg == 0) continue;
        int krow_base = seg ? K : 0;
        int arow = tid >> 2, acol = (tid & 3) << 2;
        int brow = tid >> 4, bcol = (tid & 15) << 2;
        for (int k0 = 0; k0 < Kseg; k0 += 16) {
            float4 av = *(const float4*)&Ain[(size_t)(m0 + arow) * Kseg + k0 + acol];
            As[acol + 0][arow] = av.x;
            As[acol + 1][arow] = av.y;
            As[acol + 2][arow] = av.z;
            As[acol + 3][arow] = av.w;
            float4 bv = *(const float4*)&Bw[(size_t)(krow_base + k0 + brow) * N + n0 + bcol];
            *(float4*)&Bs[brow][bcol] = bv;
            __syncthreads();
#pragma unroll
            for (int kk = 0; kk < 16; ++kk) {
                float4 af = *(const float4*)&As[kk][ty << 2];
                float4 bf = *(const float4*)&Bs[kk][tx << 2];
                float a_[4] = {af.x, af.y, af.z, af.w};
                float b_[4] = {bf.x, bf.y, bf.z, bf.w};
#pragma unroll
                for (int i = 0; i < 4; ++i)
#pragma unroll
                    for (int j = 0; j < 4; ++j) acc[i][j] += a_[i] * b_[j];
            }
            __syncthreads();
        }
    }

#pragma unroll
    for (int i = 0; i < 4; ++i) {
        int m = m0 + (ty << 2) + i;
        float rs = rowscale ? rowscale[m & rs_mask] : 1.0f;
        float4 o;
        float v[4];
#pragma unroll
        for (int j = 0; j < 4; ++j) {
            int n = n0 + (tx << 2) + j;
            float val = acc[i][j];
            if (bias) val += bias[n] * rs;
            if (relu) val = fmaxf(val, 0.0f);
            v[j] = val;
        }
        o.x = v[0]; o.y = v[1]; o.z = v[2]; o.w = v[3];
        *(float4*)&C[(size_t)m * N + n0 + (tx << 2)] = o;
    }
}

// ---------------------------------------------------------------------------
// aggpre[b,i,h] = sum_j Aw[i,j] * relu(a[b,i,h] + bb[b,j,h] + b1[h])
// ---------------------------------------------------------------------------
__global__ __launch_bounds__(256) void aggregate_kernel(
    const float* __restrict__ a, const float* __restrict__ bbv,
    const float* __restrict__ b1, const float* __restrict__ Aw,
    float* __restrict__ aggpre)
{
    int b  = blockIdx.y;
    int i0 = blockIdx.x * 4;
    int h  = threadIdx.x;
    float bias = b1[h];
    float ai[4], acc[4] = {0.f, 0.f, 0.f, 0.f};
#pragma unroll
    for (int ii = 0; ii < 4; ++ii)
        ai[ii] = a[((size_t)b * NR + i0 + ii) * HID + h] + bias;
    const float* bbb = &bbv[(size_t)b * NR * HID + h];
#pragma unroll 2
    for (int j = 0; j < NR; ++j) {
        float bj = bbb[(size_t)j * HID];
#pragma unroll
        for (int ii = 0; ii < 4; ++ii) {
            float pre = fmaxf(ai[ii] + bj, 0.0f);
            acc[ii] += Aw[(i0 + ii) * NR + j] * pre;
        }
    }
#pragma unroll
    for (int ii = 0; ii < 4; ++ii)
        aggpre[((size_t)b * NR + i0 + ii) * HID + h] = acc[ii];
}

// ---------------------------------------------------------------------------
// h = layernorm(hsrc_row + u) * g + b   (hsrc per full row)
// ---------------------------------------------------------------------------
__global__ __launch_bounds__(256) void resid_ln_kernel(
    float* __restrict__ h, const float* __restrict__ u,
    const float* __restrict__ g, const float* __restrict__ bta)
{
    int row = blockIdx.x;
    int t = threadIdx.x;
    size_t idx = (size_t)row * HID + t;
    float v = h[idx] + u[idx];
    __shared__ float red[8];
    float s = v;
#pragma unroll
    for (int off = 32; off; off >>= 1) s += __shfl_xor(s, off);
    int wave = t >> 6, lane = t & 63;
    if (lane == 0) red[wave] = s;
    __syncthreads();
    float mu = (red[0] + red[1] + red[2] + red[3]) * (1.0f / HID);
    float d = v - mu;
    float s2 = d * d;
#pragma unroll
    for (int off = 32; off; off >>= 1) s2 += __shfl_xor(s2, off);
    if (lane == 0) red[4 + wave] = s2;
    __syncthreads();
    float var = (red[4] + red[5] + red[6] + red[7]) * (1.0f / HID);
    h[idx] = d * rsqrtf(var + 1e-5f) * g[t] + bta[t];
}

// Layer-0 variant: h[row] = LN(h0[b] + u[row]), h0 broadcast per batch
__global__ __launch_bounds__(256) void resid_ln_bcast_kernel(
    float* __restrict__ h, const float* __restrict__ h0g, const float* __restrict__ u,
    const float* __restrict__ g, const float* __restrict__ bta)
{
    int row = blockIdx.x;           // b*NR+i
    int b = row >> 7;
    int t = threadIdx.x;
    size_t idx = (size_t)row * HID + t;
    float v = h0g[b * HID + t] + u[idx];
    __shared__ float red[8];
    float s = v;
#pragma unroll
    for (int off = 32; off; off >>= 1) s += __shfl_xor(s, off);
    int wave = t >> 6, lane = t & 63;
    if (lane == 0) red[wave] = s;
    __syncthreads();
    float mu = (red[0] + red[1] + red[2] + red[3]) * (1.0f / HID);
    float d = v - mu;
    float s2 = d * d;
#pragma unroll
    for (int off = 32; off; off >>= 1) s2 += __shfl_xor(s2, off);
    if (lane == 0) red[4 + wave] = s2;
    __syncthreads();
    float var = (red[4] + red[5] + red[6] + red[7]) * (1.0f / HID);
    h[idx] = d * rsqrtf(var + 1e-5f) * g[t] + bta[t];
}

// ---------------------------------------------------------------------------
// Attention scores + softmax
// ---------------------------------------------------------------------------
__global__ __launch_bounds__(128) void attn_score_kernel(
    const float* __restrict__ q, const float* __restrict__ k, float* __restrict__ S)
{
    int i  = blockIdx.x;
    int bh = blockIdx.y;
    int b = bh >> 2, hd = bh & 3;
    int j = threadIdx.x;
    __shared__ float qs[DHD];
    if (j < DHD) qs[j] = q[((size_t)(b * NR + i)) * HID + hd * DHD + j];
    __syncthreads();
    const float4* k4 = (const float4*)&k[((size_t)(b * NR + j)) * HID + hd * DHD];
    const float4* q4 = (const float4*)qs;
    float acc = 0.f;
#pragma unroll
    for (int d4 = 0; d4 < DHD / 4; ++d4) {
        float4 kv = k4[d4];
        float4 qv = q4[d4];
        acc += qv.x * kv.x + qv.y * kv.y + qv.z * kv.z + qv.w * kv.w;
    }
    acc *= 0.125f;
    __shared__ float red[4];
    float m = acc;
#pragma unroll
    for (int off = 32; off; off >>= 1) m = fmaxf(m, __shfl_xor(m, off));
    if ((j & 63) == 0) red[j >> 6] = m;
    __syncthreads();
    m = fmaxf(red[0], red[1]);
    float e = expf(acc - m);
    float s = e;
#pragma unroll
    for (int off = 32; off; off >>= 1) s += __shfl_xor(s, off);
    if ((j & 63) == 0) red[2 + (j >> 6)] = s;
    __syncthreads();
    s = red[2] + red[3];
    S[((size_t)bh * NR + i) * NR + j] = e / s;
}

__global__ __launch_bounds__(256) void attn_pv_kernel(
    const float* __restrict__ S, const float* __restrict__ v, float* __restrict__ pooled)
{
    int bi = blockIdx.x;
    int b = bi >> 7, i = bi & 127;
    int t = threadIdx.x;
    int hd = t >> 6;
    const float* Prow = &S[(((size_t)(b * NHD + hd)) * NR + i) * NR];
    const float* vb = &v[(size_t)b * NR * HID + t];
    float acc = 0.f;
#pragma unroll 4
    for (int j = 0; j < NR; ++j) acc += Prow[j] * vb[(size_t)j * HID];
    pooled[(size_t)bi * HID + t] = acc;
}

// ---------------------------------------------------------------------------
// Tail: per-batch. g = mean_i pooled; s1 = g@Wo+bo; s2 = relu(s1@roW1+rob1);
// logits = s2@roW2+rob2; out = softmax(logits)
// ---------------------------------------------------------------------------
__global__ __launch_bounds__(256) void tail_kernel(
    const float* __restrict__ pooled,
    const float* __restrict__ Wo, const float* __restrict__ bo,
    const float* __restrict__ roW1, const float* __restrict__ rob1,
    const float* __restrict__ roW2, const float* __restrict__ rob2,
    float* __restrict__ out)
{
    int b = blockIdx.x;
    int t = threadIdx.x;
    int w = t >> 6, l = t & 63;
    __shared__ float g0s[HID], s1s[HID], s2s[HID];
    __shared__ float red[1024];

    // mean over i: wave w sums i in [32w, 32w+32), lane l -> cols 4l..4l+3
    {
        float4 acc = {0.f, 0.f, 0.f, 0.f};
        const float* pb = &pooled[((size_t)b * NR + w * 32) * HID + l * 4];
#pragma unroll 8
        for (int ii = 0; ii < 32; ++ii) {
            float4 pv = *(const float4*)(pb + (size_t)ii * HID);
            acc.x += pv.x; acc.y += pv.y; acc.z += pv.z; acc.w += pv.w;
        }
        *(float4*)&red[w * 256 + l * 4] = acc;
        __syncthreads();
        g0s[t] = (red[t] + red[256 + t] + red[512 + t] + red[768 + t]) * (1.0f / NR);
        __syncthreads();
    }

    gemv256(g0s, Wo, HID, bo, 0, s1s, red);
    gemv256(s1s, roW1, HID, rob1, 1, s2s, red);

    // logits: N=128. lane l -> outputs 2l,2l+1; wave w -> k quarter.
    {
        float2 acc = {0.f, 0.f};
        const float* Wp = roW2 + (size_t)(w * 64) * NR + l * 2;
        const float* xp = s2s + w * 64;
#pragma unroll 8
        for (int kk = 0; kk < 64; ++kk) {
            float xv = xp[kk];
            float2 wv = *(const float2*)(Wp + (size_t)kk * NR);
            acc.x += xv * wv.x; acc.y += xv * wv.y;
        }
        *(float2*)&red[w * 128 + l * 2] = acc;
        __syncthreads();
    }

    float logit = -1e30f;
    if (t < NR) logit = red[t] + red[128 + t] + red[256 + t] + red[384 + t] + rob2[t];
    __syncthreads();
    // softmax over t<128 (waves 0,1)
    float m = logit;
#pragma unroll
    for (int off = 32; off; off >>= 1) m = fmaxf(m, __shfl_xor(m, off));
    if (l == 0) red[w] = m;
    __syncthreads();
    m = fmaxf(red[0], red[1]);
    float e = (t < NR) ? expf(logit - m) : 0.0f;
    float ssum = e;
#pragma unroll
    for (int off = 32; off; off >>= 1) ssum += __shfl_xor(ssum, off);
    if (l == 0) red[4 + w] = ssum;
    __syncthreads();
    float tot = red[4] + red[5];
    if (t < NR) out[b * NR + t] = e / tot;
}

// ---------------------------------------------------------------------------
extern "C" void kernel_launch(void* const* d_in, const int* in_sizes, int n_in,
                              void* d_out, int out_size, void* d_ws, size_t ws_size,
                              hipStream_t stream)
{
    const float* x        = (const float*)d_in[0];
    const float* We       = (const float*)d_in[1];
    const float* be       = (const float*)d_in[2];
    const float* msg_W1   = (const float*)d_in[3];
    const float* msg_b1   = (const float*)d_in[4];
    const float* msg_W2   = (const float*)d_in[5];
    const float* msg_b2   = (const float*)d_in[6];
    const float* upd_W1   = (const float*)d_in[7];
    const float* upd_b1   = (const float*)d_in[8];
    const float* upd_W2   = (const float*)d_in[9];
    const float* upd_b2   = (const float*)d_in[10];
    const float* ln_g     = (const float*)d_in[11];
    const float* ln_b     = (const float*)d_in[12];
    const float* rule_adj = (const float*)d_in[13];
    const float* Wq       = (const float*)d_in[14];
    const float* bq       = (const float*)d_in[15];
    const float* Wk       = (const float*)d_in[16];
    const float* bk       = (const float*)d_in[17];
    const float* Wv       = (const float*)d_in[18];
    const float* bv       = (const float*)d_in[19];
    const float* Wo       = (const float*)d_in[20];
    const float* bo       = (const float*)d_in[21];
    const float* ro_W1    = (const float*)d_in[22];
    const float* ro_b1    = (const float*)d_in[23];
    const float* ro_W2    = (const float*)d_in[24];
    const float* ro_b2    = (const float*)d_in[25];
    float* out = (float*)d_out;

    constexpr size_t SZ = (size_t)NB * NR * HID;  // 262144
    float* ws   = (float*)d_ws;
    float* h    = ws;
    float* buf1 = h    + SZ;        // a  / q
    float* buf2 = buf1 + SZ;        // bb / k
    float* buf3 = buf2 + SZ;        // aggpre / v
    float* buf4 = buf3 + SZ;        // agg / pooled
    float* buf5 = buf4 + SZ;        // u1
    float* buf6 = buf5 + SZ;        // u
    float* Sbuf = buf6 + SZ;        // [B,NH,R,R]
    float* Aw   = Sbuf + (size_t)NB * NHD * NR * NR;
    float* rsum = Aw + NR * NR;
    float* h0g  = rsum + NR;
    float* c0g  = h0g + NB * HID;
    float* c1g  = c0g + NB * HID;

    dim3 gemm_block(256);

    adj_kernel<<<dim3(NR), 128, 0, stream>>>(rule_adj, Aw, rsum);

    // ---- layer 0 (collapsed) ----
    head_kernel<<<dim3(NB), 256, 0, stream>>>(
        x, We, be, msg_W1, msg_b1, msg_W2, msg_b2, upd_W1, h0g, c0g, c1g);

    u1_bcast_kernel<<<dim3(NR, NB), 256, 0, stream>>>(c0g, c1g, rsum, upd_b1, buf5);

    gemm_fused<<<dim3(4, 16, 1), gemm_block, 0, stream>>>(
        buf5, HID, nullptr, 0,
        upd_W2, nullptr, nullptr,
        upd_b2, nullptr, nullptr,
        buf6, nullptr, nullptr,
        HID, nullptr, 0, 0);

    resid_ln_bcast_kernel<<<dim3(NB * NR), 256, 0, stream>>>(h, h0g, buf6, ln_g, ln_b);

    // ---- layers 1..2 ----
    for (int l = 1; l < NL; ++l) {
        const float* mW1 = msg_W1 + (size_t)l * 2 * HID * HID;
        const float* mb1 = msg_b1 + (size_t)l * HID;
        const float* mW2 = msg_W2 + (size_t)l * HID * HID;
        const float* mb2 = msg_b2 + (size_t)l * HID;
        const float* uW1 = upd_W1 + (size_t)l * 2 * HID * HID;
        const float* ub1 = upd_b1 + (size_t)l * HID;
        const float* uW2 = upd_W2 + (size_t)l * HID * HID;
        const float* ub2 = upd_b2 + (size_t)l * HID;
        const float* lg  = ln_g + (size_t)l * HID;
        const float* lb  = ln_b + (size_t)l * HID;

        gemm_fused<<<dim3(4, 16, 2), gemm_block, 0, stream>>>(
            h, HID, nullptr, 0,
            mW1, mW1 + (size_t)HID * HID, nullptr,
            nullptr, nullptr, nullptr,
            buf1, buf2, nullptr,
            HID, nullptr, 0, 0);

        aggregate_kernel<<<dim3(NR / 4, NB), 256, 0, stream>>>(buf1, buf2, mb1, Aw, buf3);

        gemm_fused<<<dim3(4, 16, 1), gemm_block, 0, stream>>>(
            buf3, HID, nullptr, 0,
            mW2, nullptr, nullptr,
            mb2, nullptr, nullptr,
            buf4, nullptr, nullptr,
            HID, rsum, NR - 1, 0);

        gemm_fused<<<dim3(4, 16, 1), gemm_block, 0, stream>>>(
            h, HID, buf4, HID,
            uW1, nullptr, nullptr,
            ub1, nullptr, nullptr,
            buf5, nullptr, nullptr,
            HID, nullptr, 0, 1);

        gemm_fused<<<dim3(4, 16, 1), gemm_block, 0, stream>>>(
            buf5, HID, nullptr, 0,
            uW2, nullptr, nullptr,
            ub2, nullptr, nullptr,
            buf6, nullptr, nullptr,
            HID, nullptr, 0, 0);

        resid_ln_kernel<<<dim3(NB * NR), 256, 0, stream>>>(h, buf6, lg, lb);
    }

    // ---- attention ----
    gemm_fused<<<dim3(4, 16, 3), gemm_block, 0, stream>>>(
        h, HID, nullptr, 0,
        Wq, Wk, Wv,
        bq, bk, bv,
        buf1, buf2, buf3,
        HID, nullptr, 0, 0);

    attn_score_kernel<<<dim3(NR, NB * NHD), 128, 0, stream>>>(buf1, buf2, Sbuf);
    attn_pv_kernel<<<dim3(NB * NR), 256, 0, stream>>>(Sbuf, buf3, buf4);

    // ---- tail (mean commuted past Wo) ----
    tail_kernel<<<dim3(NB), 256, 0, stream>>>(
        buf4, Wo, bo, ro_W1, ro_b1, ro_W2, ro_b2, out);
}